// Round 8
// baseline (104.315 us; speedup 1.0000x reference)
//
#include <hip/hip_runtime.h>
#include <hip/hip_bf16.h>
#include <math.h>

#define H   1024
#define V   50257
#define L   64
#define H2  2048
#define H3  3072

typedef float float4v __attribute__((ext_vector_type(4)));

// ---- workspace layout (float offsets) ----
#define WS_AA          128      // 2048 (attn_applied)
#define WS_X           2176     // 1024
#define WS_GRU         3200     // 2048 (gru_out, 16B-aligned copy)
#define WS_LOGITS      5248     // 50257
#define WS_RED         55552    // 2048 (1024 blocks x (m,s))

#define GEMV_BLOCKS 1024
#define GEMV_WAVES  (GEMV_BLOCKS * 4)     // 4096

__device__ inline float waveReduceSum(float v) {
#pragma unroll
    for (int off = 32; off > 0; off >>= 1) v += __shfl_down(v, off, 64);
    return v;  // lane 0 holds sum
}
__device__ inline float waveAllMax(float v) {
#pragma unroll
    for (int off = 32; off > 0; off >>= 1) v = fmaxf(v, __shfl_xor(v, off, 64));
    return v;
}
__device__ inline float waveAllSum(float v) {
#pragma unroll
    for (int off = 32; off > 0; off >>= 1) v += __shfl_xor(v, off, 64);
    return v;
}
__device__ inline void lse_combine(float& m, float& s, float m2, float s2) {
    float M = fmaxf(m, m2);
    s = s * expf(m - M) + s2 * expf(m2 - M);
    m = M;
}

// K12: fused attn logits + softmax + attn_applied; grid=8, block=256.
// Each block redundantly computes all 64 logits (attn_W is 768KB; 8 blocks
// -> 6MB extra L2/HBM, ~1us). Waves process their 16 rows in PAIRS so 24
// global loads are in flight per step (R5's serial-row version was
// latency-bound; this is the fix). Then softmax in wave 0, then each block
// does its 256 columns of attn_applied.
__global__ __launch_bounds__(256) void k_attn_fused(
        const int* __restrict__ tok_p, const float* __restrict__ hidden,
        const float* __restrict__ emb, const float* __restrict__ attn_W,
        const float* __restrict__ attn_b, const float* __restrict__ eo,
        float* __restrict__ ws, float* __restrict__ d_out) {
    __shared__ float4 c34[768];
    __shared__ float lgt[64];
    __shared__ float aw[64];
    int tid = threadIdx.x;
    int lane = tid & 63, wid = tid >> 6;
    int tok = tok_p[0];
    const float4* emb4 = (const float4*)(emb + (size_t)tok * H);
    const float4* hid4 = (const float4*)hidden;
#pragma unroll
    for (int k = 0; k < 3; ++k) {
        int idx = tid + k * 256;                     // 0..767 float4s of cat3
        c34[idx] = (idx < 256) ? emb4[idx] : hid4[idx - 256];
    }
    __syncthreads();
    // wave wid owns rows wid*16 .. wid*16+15, processed as 8 pairs
    for (int pr = 0; pr < 8; ++pr) {
        int r0 = wid * 16 + 2 * pr;
        int r1 = r0 + 1;
        const float4* wa = (const float4*)(attn_W + (size_t)r0 * H3);
        const float4* wb = (const float4*)(attn_W + (size_t)r1 * H3);
        float a0 = 0.f, a1 = 0.f;
#pragma unroll
        for (int j = 0; j < 12; ++j) {
            int idx = lane + j * 64;                 // 0..767
            float4 c = c34[idx];
            float4 u = wa[idx];
            float4 v = wb[idx];
            a0 += c.x * u.x + c.y * u.y + c.z * u.z + c.w * u.w;
            a1 += c.x * v.x + c.y * v.y + c.z * v.z + c.w * v.w;
        }
        a0 = waveReduceSum(a0);
        a1 = waveReduceSum(a1);
        if (lane == 0) {
            lgt[r0] = a0 + attn_b[r0];
            lgt[r1] = a1 + attn_b[r1];
        }
    }
    __syncthreads();
    if (tid < 64) {                                  // wave 0: softmax64
        float x = lgt[tid];
        float m = waveAllMax(x);
        float e = expf(x - m);
        float sden = waveAllSum(e);
        float w = e / sden;
        aw[tid] = w;
        if (blockIdx.x == 0) d_out[V + H2 + tid] = w;   // attn_weights output
    }
    __syncthreads();
    int j = blockIdx.x * 256 + tid;                  // 0..2047
    float acc = 0.f;
#pragma unroll 8
    for (int l = 0; l < L; ++l) acc += aw[l] * eo[l * H2 + j];
    ws[WS_AA + j] = acc;
}

// K3: x[r] = relu(dot(comb, comb_W[r,:]) + comb_b[r]); grid=256 (1 wave/row)
__global__ __launch_bounds__(256) void k_comb_relu(
        const int* __restrict__ tok_p, const float* __restrict__ emb,
        const float* __restrict__ comb_W, const float* __restrict__ comb_b,
        float* __restrict__ ws) {
    int tid = threadIdx.x;
    int lane = tid & 63, wid = tid >> 6;
    int r = blockIdx.x * 4 + wid;
    int tok = tok_p[0];
    const float4* emb4 = (const float4*)(emb + (size_t)tok * H);
    const float4* aa4  = (const float4*)(ws + WS_AA);
    const float4v* w4  = (const float4v*)(comb_W + (size_t)r * H3);
    float acc = 0.f;
#pragma unroll
    for (int k = 0; k < 12; ++k) {
        int idx = lane + k * 64;                // 0..767
        float4 c = (idx < 256) ? emb4[idx] : aa4[idx - 256];
        float4v w = __builtin_nontemporal_load(&w4[idx]);
        acc += c.x * w.x + c.y * w.y + c.z * w.z + c.w * w.w;
    }
    acc = waveReduceSum(acc);
    if (lane == 0) ws[WS_X + r] = fmaxf(acc + comb_b[r], 0.f);
}

// K4: both GRU cells, one wave per output element; grid=512, block=256
__global__ __launch_bounds__(256) void k_gru(
        const float* __restrict__ hidden,
        const float* __restrict__ Wih_f, const float* __restrict__ Whh_f,
        const float* __restrict__ bih_f, const float* __restrict__ bhh_f,
        const float* __restrict__ Wih_b, const float* __restrict__ Whh_b,
        const float* __restrict__ bih_b, const float* __restrict__ bhh_b,
        float* __restrict__ d_out, float* __restrict__ ws) {
    int tid = threadIdx.x;
    int lane = tid & 63, wid = tid >> 6;
    int w = blockIdx.x * 4 + wid;               // 0..2047
    int dir = w >> 10;                          // 0 = fwd, 1 = bwd
    int i = w & (H - 1);
    const float* Wih = dir ? Wih_b : Wih_f;
    const float* Whh = dir ? Whh_b : Whh_f;
    const float* bih = dir ? bih_b : bih_f;
    const float* bhh = dir ? bhh_b : bhh_f;
    const float* h = hidden + dir * H;
    const float4* x4  = (const float4*)(ws + WS_X);
    const float4* h4  = (const float4*)h;
    const float4v* wi0 = (const float4v*)(Wih + (size_t)i * H);
    const float4v* wi1 = (const float4v*)(Wih + (size_t)(H + i) * H);
    const float4v* wi2 = (const float4v*)(Wih + (size_t)(2 * H + i) * H);
    const float4v* wh0 = (const float4v*)(Whh + (size_t)i * H);
    const float4v* wh1 = (const float4v*)(Whh + (size_t)(H + i) * H);
    const float4v* wh2 = (const float4v*)(Whh + (size_t)(2 * H + i) * H);
    float a0 = 0, a1 = 0, a2 = 0, b0 = 0, b1 = 0, b2 = 0;
#pragma unroll
    for (int k = 0; k < 4; ++k) {
        int idx = lane + k * 64;                // 0..255 float4s
        float4 xv = x4[idx], hv = h4[idx];
        float4v u0 = __builtin_nontemporal_load(&wi0[idx]);
        float4v u1 = __builtin_nontemporal_load(&wi1[idx]);
        float4v u2 = __builtin_nontemporal_load(&wi2[idx]);
        float4v v0 = __builtin_nontemporal_load(&wh0[idx]);
        float4v v1 = __builtin_nontemporal_load(&wh1[idx]);
        float4v v2 = __builtin_nontemporal_load(&wh2[idx]);
        a0 += xv.x*u0.x + xv.y*u0.y + xv.z*u0.z + xv.w*u0.w;
        a1 += xv.x*u1.x + xv.y*u1.y + xv.z*u1.z + xv.w*u1.w;
        a2 += xv.x*u2.x + xv.y*u2.y + xv.z*u2.z + xv.w*u2.w;
        b0 += hv.x*v0.x + hv.y*v0.y + hv.z*v0.z + hv.w*v0.w;
        b1 += hv.x*v1.x + hv.y*v1.y + hv.z*v1.z + hv.w*v1.w;
        b2 += hv.x*v2.x + hv.y*v2.y + hv.z*v2.z + hv.w*v2.w;
    }
    a0 = waveReduceSum(a0); a1 = waveReduceSum(a1); a2 = waveReduceSum(a2);
    b0 = waveReduceSum(b0); b1 = waveReduceSum(b1); b2 = waveReduceSum(b2);
    if (lane == 0) {
        float ir = a0 + bih[i],     iz = a1 + bih[H + i], in_ = a2 + bih[2 * H + i];
        float hr = b0 + bhh[i],     hz = b1 + bhh[H + i], hn  = b2 + bhh[2 * H + i];
        float r = 1.f / (1.f + expf(-(ir + hr)));
        float z = 1.f / (1.f + expf(-(iz + hz)));
        float n = tanhf(in_ + r * hn);
        float hv = (1.f - z) * n + z * h[i];
        d_out[V + dir * H + i] = hv;            // new_hidden / gru_out
        ws[WS_GRU + dir * H + i] = hv;          // aligned copy for GEMV
    }
}

// K5: vocab GEMV (grid-stride, 1 wave/row, 2 rows in flight) + per-block
// (m,s). Exactly R2's proven form: strided pair (v, v+4096), all-NT loads,
// flat interleaved body (16 loads in flight).
__global__ __launch_bounds__(256) void k_gemv_lse(
        const float* __restrict__ out_W, const float* __restrict__ out_b,
        float* __restrict__ ws) {
    int tid = threadIdx.x;
    int lane = tid & 63, wid = tid >> 6;
    int gw = blockIdx.x * 4 + wid;                   // global wave id 0..4095
    const float4* g4 = (const float4*)(ws + WS_GRU);
    float m = -3.0e38f, s = 0.f;
    for (int v = gw; v < V; v += 2 * GEMV_WAVES) {
        int v2 = v + GEMV_WAVES;
        const float4v* w4  = (const float4v*)(out_W + (size_t)v * H2);
        float acc0 = 0.f, acc1 = 0.f;
#pragma unroll
        for (int k = 0; k < 8; ++k) {
            int idx = lane + k * 64;                 // 0..511 float4s
            float4 g = g4[idx];
            float4v w = __builtin_nontemporal_load(&w4[idx]);
            acc0 += g.x * w.x + g.y * w.y + g.z * w.z + g.w * w.w;
        }
        if (v2 < V) {
            const float4v* w4b = (const float4v*)(out_W + (size_t)v2 * H2);
#pragma unroll
            for (int k = 0; k < 8; ++k) {
                int idx = lane + k * 64;
                float4 g = g4[idx];
                float4v w = __builtin_nontemporal_load(&w4b[idx]);
                acc1 += g.x * w.x + g.y * w.y + g.z * w.z + g.w * w.w;
            }
        }
        acc0 = waveReduceSum(acc0);
        acc1 = waveReduceSum(acc1);
        if (lane == 0) {
            float logit = acc0 + out_b[v];
            ws[WS_LOGITS + v] = logit;
            float M = fmaxf(m, logit);
            s = s * expf(m - M) + expf(logit - M);
            m = M;
            if (v2 < V) {
                float logit2 = acc1 + out_b[v2];
                ws[WS_LOGITS + v2] = logit2;
                M = fmaxf(m, logit2);
                s = s * expf(m - M) + expf(logit2 - M);
                m = M;
            }
        }
    }
    __shared__ float mm[4], ss[4];
    if (lane == 0) { mm[wid] = m; ss[wid] = s; }
    __syncthreads();
    if (tid == 0) {
        float M = mm[0], S = ss[0];
        lse_combine(M, S, mm[1], ss[1]);
        lse_combine(M, S, mm[2], ss[2]);
        lse_combine(M, S, mm[3], ss[3]);
        ws[WS_RED + 2 * blockIdx.x]     = M;
        ws[WS_RED + 2 * blockIdx.x + 1] = S;
    }
}

// K6: each block redundantly combines 1024 (m,s) pairs (L2-hit), subtracts C
__global__ __launch_bounds__(256) void k_lse_sub(const float* __restrict__ ws,
                                                 float* __restrict__ d_out) {
    int tid = threadIdx.x;
    int lane = tid & 63, wid = tid >> 6;
    float m = -3.0e38f, s = 0.f;
#pragma unroll
    for (int k = 0; k < 4; ++k) {
        int i = tid + k * 256;                       // 0..1023
        lse_combine(m, s, ws[WS_RED + 2 * i], ws[WS_RED + 2 * i + 1]);
    }
#pragma unroll
    for (int off = 32; off > 0; off >>= 1) {
        float m2 = __shfl_xor(m, off, 64);
        float s2 = __shfl_xor(s, off, 64);
        lse_combine(m, s, m2, s2);
    }
    __shared__ float mm[4], ss[4], Csh;
    if (lane == 0) { mm[wid] = m; ss[wid] = s; }
    __syncthreads();
    if (tid == 0) {
        float M = mm[0], S = ss[0];
        lse_combine(M, S, mm[1], ss[1]);
        lse_combine(M, S, mm[2], ss[2]);
        lse_combine(M, S, mm[3], ss[3]);
        Csh = M + logf(S);
    }
    __syncthreads();
    float C = Csh;
    int v = blockIdx.x * 256 + tid;
    if (v < V) d_out[v] = ws[WS_LOGITS + v] - C;
}

extern "C" void kernel_launch(void* const* d_in, const int* in_sizes, int n_in,
                              void* d_out, int out_size, void* d_ws, size_t ws_size,
                              hipStream_t stream) {
    const int*   tok     = (const int*)  d_in[0];
    const float* hidden  = (const float*)d_in[1];
    // d_in[2] = encoder_output (unused by the reference)
    const float* enc_outs= (const float*)d_in[3];
    const float* emb     = (const float*)d_in[4];
    const float* attn_W  = (const float*)d_in[5];
    const float* attn_b  = (const float*)d_in[6];
    const float* comb_W  = (const float*)d_in[7];
    const float* comb_b  = (const float*)d_in[8];
    const float* Wih_f   = (const float*)d_in[9];
    const float* Whh_f   = (const float*)d_in[10];
    const float* bih_f   = (const float*)d_in[11];
    const float* bhh_f   = (const float*)d_in[12];
    const float* Wih_b   = (const float*)d_in[13];
    const float* Whh_b   = (const float*)d_in[14];
    const float* bih_b   = (const float*)d_in[15];
    const float* bhh_b   = (const float*)d_in[16];
    const float* out_W   = (const float*)d_in[17];
    const float* out_b   = (const float*)d_in[18];
    float* out = (float*)d_out;
    float* ws  = (float*)d_ws;

    hipLaunchKernelGGL(k_attn_fused, dim3(8), dim3(256), 0, stream,
                       tok, hidden, emb, attn_W, attn_b, enc_outs, ws, out);
    hipLaunchKernelGGL(k_comb_relu, dim3(256), dim3(256), 0, stream,
                       tok, emb, comb_W, comb_b, ws);
    hipLaunchKernelGGL(k_gru, dim3(512), dim3(256), 0, stream,
                       hidden, Wih_f, Whh_f, bih_f, bhh_f,
                       Wih_b, Whh_b, bih_b, bhh_b, out, ws);
    hipLaunchKernelGGL(k_gemv_lse, dim3(GEMV_BLOCKS), dim3(256), 0, stream,
                       out_W, out_b, ws);
    hipLaunchKernelGGL(k_lse_sub, dim3(197), dim3(256), 0, stream, ws, out);
}

// Round 9
// 93.480 us; speedup vs baseline: 1.1159x; 1.1159x over previous
//
#include <hip/hip_runtime.h>
#include <hip/hip_bf16.h>
#include <math.h>

#define H   1024
#define V   50257
#define L   64
#define H2  2048
#define H3  3072

typedef float float4v __attribute__((ext_vector_type(4)));

// ---- workspace layout (float offsets) ----
#define WS_ATTN_LOGITS 0        // 64
#define WS_AA          128      // 2048 (attn_applied)
#define WS_X           2176     // 1024
#define WS_GRU         3200     // 2048 (gru_out, 16B-aligned copy)
#define WS_LOGITS      5248     // 50257
#define WS_RED         55552    // 2048 (1024 blocks x (m,s))

#define GEMV_BLOCKS 1024
#define GEMV_WAVES  (GEMV_BLOCKS * 4)     // 4096

__device__ inline float waveReduceSum(float v) {
#pragma unroll
    for (int off = 32; off > 0; off >>= 1) v += __shfl_down(v, off, 64);
    return v;  // lane 0 holds sum
}
__device__ inline float waveAllMax(float v) {
#pragma unroll
    for (int off = 32; off > 0; off >>= 1) v = fmaxf(v, __shfl_xor(v, off, 64));
    return v;
}
__device__ inline float waveAllSum(float v) {
#pragma unroll
    for (int off = 32; off > 0; off >>= 1) v += __shfl_xor(v, off, 64);
    return v;
}
__device__ inline void lse_combine(float& m, float& s, float m2, float s2) {
    float M = fmaxf(m, m2);
    s = s * expf(m - M) + s2 * expf(m2 - M);
    m = M;
}

// K1: attn logits[b] = dot(cat3, attn_W[b,:]) + attn_b[b]; grid=64, block=256
__global__ __launch_bounds__(256) void k_attn_logits(
        const int* __restrict__ tok_p, const float* __restrict__ hidden,
        const float* __restrict__ emb, const float* __restrict__ attn_W,
        const float* __restrict__ attn_b, float* __restrict__ ws) {
    int b = blockIdx.x;
    int tid = threadIdx.x;
    int tok = tok_p[0];
    const float4* w4   = (const float4*)(attn_W + (size_t)b * H3);
    const float4* emb4 = (const float4*)(emb + (size_t)tok * H);
    const float4* hid4 = (const float4*)hidden;
    float acc = 0.f;
#pragma unroll
    for (int k = 0; k < 3; ++k) {
        int idx = tid + k * 256;                 // float4 index into cat3 (768)
        float4 c = (idx < 256) ? emb4[idx] : hid4[idx - 256];
        float4 w = w4[idx];
        acc += c.x * w.x + c.y * w.y + c.z * w.z + c.w * w.w;
    }
    __shared__ float red[4];
    float p = waveReduceSum(acc);
    int lane = tid & 63, wid = tid >> 6;
    if (lane == 0) red[wid] = p;
    __syncthreads();
    if (tid == 0) ws[WS_ATTN_LOGITS + b] = red[0] + red[1] + red[2] + red[3] + attn_b[b];
}

// K2: softmax over 64 logits (redundant per block) + attn_applied; grid=8, block=256
__global__ __launch_bounds__(256) void k_softmax_applied(
        const float* __restrict__ eo, float* __restrict__ ws,
        float* __restrict__ d_out) {
    __shared__ float aw[64];
    int tid = threadIdx.x;
    if (tid < 64) {
        float x = ws[WS_ATTN_LOGITS + tid];
        float m = waveAllMax(x);
        float e = expf(x - m);
        float s = waveAllSum(e);
        float w = e / s;
        aw[tid] = w;
        if (blockIdx.x == 0) d_out[V + H2 + tid] = w;   // attn_weights output
    }
    __syncthreads();
    int j = blockIdx.x * 256 + tid;                     // 0..2047
    float acc = 0.f;
#pragma unroll 8
    for (int l = 0; l < L; ++l) acc += aw[l] * eo[l * H2 + j];
    ws[WS_AA + j] = acc;
}

// K3: x[r] = relu(dot(comb, comb_W[r,:]) + comb_b[r]); grid=256 (1 wave/row)
__global__ __launch_bounds__(256) void k_comb_relu(
        const int* __restrict__ tok_p, const float* __restrict__ emb,
        const float* __restrict__ comb_W, const float* __restrict__ comb_b,
        float* __restrict__ ws) {
    int tid = threadIdx.x;
    int lane = tid & 63, wid = tid >> 6;
    int r = blockIdx.x * 4 + wid;
    int tok = tok_p[0];
    const float4* emb4 = (const float4*)(emb + (size_t)tok * H);
    const float4* aa4  = (const float4*)(ws + WS_AA);
    const float4v* w4  = (const float4v*)(comb_W + (size_t)r * H3);
    float acc = 0.f;
#pragma unroll
    for (int k = 0; k < 12; ++k) {
        int idx = lane + k * 64;                // 0..767
        float4 c = (idx < 256) ? emb4[idx] : aa4[idx - 256];
        float4v w = __builtin_nontemporal_load(&w4[idx]);
        acc += c.x * w.x + c.y * w.y + c.z * w.z + c.w * w.w;
    }
    acc = waveReduceSum(acc);
    if (lane == 0) ws[WS_X + r] = fmaxf(acc + comb_b[r], 0.f);
}

// K4: both GRU cells, one wave per output element; grid=512, block=256
__global__ __launch_bounds__(256) void k_gru(
        const float* __restrict__ hidden,
        const float* __restrict__ Wih_f, const float* __restrict__ Whh_f,
        const float* __restrict__ bih_f, const float* __restrict__ bhh_f,
        const float* __restrict__ Wih_b, const float* __restrict__ Whh_b,
        const float* __restrict__ bih_b, const float* __restrict__ bhh_b,
        float* __restrict__ d_out, float* __restrict__ ws) {
    int tid = threadIdx.x;
    int lane = tid & 63, wid = tid >> 6;
    int w = blockIdx.x * 4 + wid;               // 0..2047
    int dir = w >> 10;                          // 0 = fwd, 1 = bwd
    int i = w & (H - 1);
    const float* Wih = dir ? Wih_b : Wih_f;
    const float* Whh = dir ? Whh_b : Whh_f;
    const float* bih = dir ? bih_b : bih_f;
    const float* bhh = dir ? bhh_b : bhh_f;
    const float* h = hidden + dir * H;
    const float4* x4  = (const float4*)(ws + WS_X);
    const float4* h4  = (const float4*)h;
    const float4v* wi0 = (const float4v*)(Wih + (size_t)i * H);
    const float4v* wi1 = (const float4v*)(Wih + (size_t)(H + i) * H);
    const float4v* wi2 = (const float4v*)(Wih + (size_t)(2 * H + i) * H);
    const float4v* wh0 = (const float4v*)(Whh + (size_t)i * H);
    const float4v* wh1 = (const float4v*)(Whh + (size_t)(H + i) * H);
    const float4v* wh2 = (const float4v*)(Whh + (size_t)(2 * H + i) * H);
    float a0 = 0, a1 = 0, a2 = 0, b0 = 0, b1 = 0, b2 = 0;
#pragma unroll
    for (int k = 0; k < 4; ++k) {
        int idx = lane + k * 64;                // 0..255 float4s
        float4 xv = x4[idx], hv = h4[idx];
        float4v u0 = __builtin_nontemporal_load(&wi0[idx]);
        float4v u1 = __builtin_nontemporal_load(&wi1[idx]);
        float4v u2 = __builtin_nontemporal_load(&wi2[idx]);
        float4v v0 = __builtin_nontemporal_load(&wh0[idx]);
        float4v v1 = __builtin_nontemporal_load(&wh1[idx]);
        float4v v2 = __builtin_nontemporal_load(&wh2[idx]);
        a0 += xv.x*u0.x + xv.y*u0.y + xv.z*u0.z + xv.w*u0.w;
        a1 += xv.x*u1.x + xv.y*u1.y + xv.z*u1.z + xv.w*u1.w;
        a2 += xv.x*u2.x + xv.y*u2.y + xv.z*u2.z + xv.w*u2.w;
        b0 += hv.x*v0.x + hv.y*v0.y + hv.z*v0.z + hv.w*v0.w;
        b1 += hv.x*v1.x + hv.y*v1.y + hv.z*v1.z + hv.w*v1.w;
        b2 += hv.x*v2.x + hv.y*v2.y + hv.z*v2.z + hv.w*v2.w;
    }
    a0 = waveReduceSum(a0); a1 = waveReduceSum(a1); a2 = waveReduceSum(a2);
    b0 = waveReduceSum(b0); b1 = waveReduceSum(b1); b2 = waveReduceSum(b2);
    if (lane == 0) {
        float ir = a0 + bih[i],     iz = a1 + bih[H + i], in_ = a2 + bih[2 * H + i];
        float hr = b0 + bhh[i],     hz = b1 + bhh[H + i], hn  = b2 + bhh[2 * H + i];
        float r = 1.f / (1.f + expf(-(ir + hr)));
        float z = 1.f / (1.f + expf(-(iz + hz)));
        float n = tanhf(in_ + r * hn);
        float hv = (1.f - z) * n + z * h[i];
        d_out[V + dir * H + i] = hv;            // new_hidden / gru_out
        ws[WS_GRU + dir * H + i] = hv;          // aligned copy for GEMV
    }
}

// K5: vocab GEMV (grid-stride, 1 wave/row, 2 rows in flight) + per-block (m,s)
__global__ __launch_bounds__(256) void k_gemv_lse(
        const float* __restrict__ out_W, const float* __restrict__ out_b,
        float* __restrict__ ws) {
    int tid = threadIdx.x;
    int lane = tid & 63, wid = tid >> 6;
    int gw = blockIdx.x * 4 + wid;                   // global wave id 0..4095
    const float4* g4 = (const float4*)(ws + WS_GRU);
    float m = -3.0e38f, s = 0.f;
    for (int v = gw; v < V; v += 2 * GEMV_WAVES) {
        int v2 = v + GEMV_WAVES;
        const float4v* w4  = (const float4v*)(out_W + (size_t)v * H2);
        float acc0 = 0.f, acc1 = 0.f;
#pragma unroll
        for (int k = 0; k < 8; ++k) {
            int idx = lane + k * 64;                 // 0..511 float4s
            float4 g = g4[idx];
            float4v w = __builtin_nontemporal_load(&w4[idx]);
            acc0 += g.x * w.x + g.y * w.y + g.z * w.z + g.w * w.w;
        }
        if (v2 < V) {
            const float4v* w4b = (const float4v*)(out_W + (size_t)v2 * H2);
#pragma unroll
            for (int k = 0; k < 8; ++k) {
                int idx = lane + k * 64;
                float4 g = g4[idx];
                float4v w = __builtin_nontemporal_load(&w4b[idx]);
                acc1 += g.x * w.x + g.y * w.y + g.z * w.z + g.w * w.w;
            }
        }
        acc0 = waveReduceSum(acc0);
        acc1 = waveReduceSum(acc1);
        if (lane == 0) {
            float logit = acc0 + out_b[v];
            ws[WS_LOGITS + v] = logit;
            float M = fmaxf(m, logit);
            s = s * expf(m - M) + expf(logit - M);
            m = M;
            if (v2 < V) {
                float logit2 = acc1 + out_b[v2];
                ws[WS_LOGITS + v2] = logit2;
                M = fmaxf(m, logit2);
                s = s * expf(m - M) + expf(logit2 - M);
                m = M;
            }
        }
    }
    __shared__ float mm[4], ss[4];
    if (lane == 0) { mm[wid] = m; ss[wid] = s; }
    __syncthreads();
    if (tid == 0) {
        float M = mm[0], S = ss[0];
        lse_combine(M, S, mm[1], ss[1]);
        lse_combine(M, S, mm[2], ss[2]);
        lse_combine(M, S, mm[3], ss[3]);
        ws[WS_RED + 2 * blockIdx.x]     = M;
        ws[WS_RED + 2 * blockIdx.x + 1] = S;
    }
}

// K6: each block redundantly combines 1024 (m,s) pairs (L2-hit), subtracts C
__global__ __launch_bounds__(256) void k_lse_sub(const float* __restrict__ ws,
                                                 float* __restrict__ d_out) {
    int tid = threadIdx.x;
    int lane = tid & 63, wid = tid >> 6;
    float m = -3.0e38f, s = 0.f;
#pragma unroll
    for (int k = 0; k < 4; ++k) {
        int i = tid + k * 256;                       // 0..1023
        lse_combine(m, s, ws[WS_RED + 2 * i], ws[WS_RED + 2 * i + 1]);
    }
#pragma unroll
    for (int off = 32; off > 0; off >>= 1) {
        float m2 = __shfl_xor(m, off, 64);
        float s2 = __shfl_xor(s, off, 64);
        lse_combine(m, s, m2, s2);
    }
    __shared__ float mm[4], ss[4], Csh;
    if (lane == 0) { mm[wid] = m; ss[wid] = s; }
    __syncthreads();
    if (tid == 0) {
        float M = mm[0], S = ss[0];
        lse_combine(M, S, mm[1], ss[1]);
        lse_combine(M, S, mm[2], ss[2]);
        lse_combine(M, S, mm[3], ss[3]);
        Csh = M + logf(S);
    }
    __syncthreads();
    float C = Csh;
    int v = blockIdx.x * 256 + tid;
    if (v < V) d_out[v] = ws[WS_LOGITS + v] - C;
}

extern "C" void kernel_launch(void* const* d_in, const int* in_sizes, int n_in,
                              void* d_out, int out_size, void* d_ws, size_t ws_size,
                              hipStream_t stream) {
    const int*   tok     = (const int*)  d_in[0];
    const float* hidden  = (const float*)d_in[1];
    // d_in[2] = encoder_output (unused by the reference)
    const float* enc_outs= (const float*)d_in[3];
    const float* emb     = (const float*)d_in[4];
    const float* attn_W  = (const float*)d_in[5];
    const float* attn_b  = (const float*)d_in[6];
    const float* comb_W  = (const float*)d_in[7];
    const float* comb_b  = (const float*)d_in[8];
    const float* Wih_f   = (const float*)d_in[9];
    const float* Whh_f   = (const float*)d_in[10];
    const float* bih_f   = (const float*)d_in[11];
    const float* bhh_f   = (const float*)d_in[12];
    const float* Wih_b   = (const float*)d_in[13];
    const float* Whh_b   = (const float*)d_in[14];
    const float* bih_b   = (const float*)d_in[15];
    const float* bhh_b   = (const float*)d_in[16];
    const float* out_W   = (const float*)d_in[17];
    const float* out_b   = (const float*)d_in[18];
    float* out = (float*)d_out;
    float* ws  = (float*)d_ws;

    hipLaunchKernelGGL(k_attn_logits, dim3(64), dim3(256), 0, stream,
                       tok, hidden, emb, attn_W, attn_b, ws);
    hipLaunchKernelGGL(k_softmax_applied, dim3(8), dim3(256), 0, stream,
                       enc_outs, ws, out);
    hipLaunchKernelGGL(k_comb_relu, dim3(256), dim3(256), 0, stream,
                       tok, emb, comb_W, comb_b, ws);
    hipLaunchKernelGGL(k_gru, dim3(512), dim3(256), 0, stream,
                       hidden, Wih_f, Whh_f, bih_f, bhh_f,
                       Wih_b, Whh_b, bih_b, bhh_b, out, ws);
    hipLaunchKernelGGL(k_gemv_lse, dim3(GEMV_BLOCKS), dim3(256), 0, stream,
                       out_W, out_b, ws);
    hipLaunchKernelGGL(k_lse_sub, dim3(197), dim3(256), 0, stream, ws, out);
}